// Round 13
// baseline (729.595 us; speedup 1.0000x reference)
//
#include <hip/hip_runtime.h>
#include <hip/hip_fp16.h>

// ---------------------------------------------------------------------------
// GCN 3-layer forward — PLANAR feature layout [8 planes][N][16 halfs].
// Slice s of node n lives at plane s, 32B/row -> per-XCD gather working set
// is 3.2MB (L2-resident). Agg block b&7 = slice (round-robin -> XCD k).
//   g_l = dinv * h_l (fp16, planar). agg[dst] = sum_src g[src] + g[dst]
//   h_{l+1} = relu( dinv[dst]*(agg @ W) + b ); layers 1,2 store dinv*h.
// ELL indices read nontemporal (don't evict plane); agg output nt-stored.
// GEMM: MFMA 32x32x16, Wt direct from global; layer3 fused with mean-pool.
// ---------------------------------------------------------------------------

#define MAXDEG 64
#define NBUCKMAX 512
#define STAGE 32
#define BUCKCAP 8192

typedef _Float16 f16x8 __attribute__((ext_vector_type(8)));
typedef float f32x16 __attribute__((ext_vector_type(16)));
typedef float f32x2 __attribute__((ext_vector_type(2)));   // clang-native for nt store

// ---- weights fp32->fp16 TRANSPOSED (Wt[f][k] = W[k][f]) + zero-inits -------
__global__ void k_cvtw(const float* __restrict__ W1, const float* __restrict__ W2,
                       const float* __restrict__ W3, __half* __restrict__ o1,
                       __half* __restrict__ o2, __half* __restrict__ o3,
                       float* __restrict__ pooled, float* __restrict__ gcnt,
                       int* __restrict__ gcur) {
    int i = blockIdx.x * blockDim.x + threadIdx.x;   // 16384, i = f*128+k
    int src = ((i & 127) << 7) + (i >> 7);           // W[k][f]
    o1[i] = __float2half_rn(W1[src]);
    o2[i] = __float2half_rn(W2[src]);
    o3[i] = __float2half_rn(W3[src]);
    pooled[i] = 0.f;
    if (i < 128) gcnt[i] = 0.f;
    if (i < NBUCKMAX) gcur[i] = 0;
}

// ---- pass A: bucket edges into per-bucket record regions -------------------
__global__ __launch_bounds__(256) void k_bucket(const int* __restrict__ row,
                                                const int* __restrict__ col,
                                                int E, int nbuck,
                                                int* __restrict__ gcur,
                                                int* __restrict__ recs) {
    __shared__ int stage[NBUCKMAX][STAGE];   // 64 KB
    __shared__ int scur[NBUCKMAX];
    int t = threadIdx.x;
    for (int i = t; i < NBUCKMAX; i += 256) scur[i] = 0;
    __syncthreads();

    int nblk = gridDim.x;
    int chunk = (((E + nblk - 1) / nblk) + 255) & ~255;
    int e0 = blockIdx.x * chunk;
    int e1 = e0 + chunk; if (e1 > E) e1 = E;

    for (int base = e0; base < e1; base += 256) {
        int e = base + t;
        if (e < e1) {
            int s = row[e], d = col[e];
            int b = d >> 8;
            int rec = (s << 8) | (d & 255);
            int slot = atomicAdd(&scur[b], 1);
            if (slot < STAGE) {
                stage[b][slot] = rec;
            } else {
                int gp = atomicAdd(&gcur[b], 1);
                if (gp < BUCKCAP) recs[(size_t)b * BUCKCAP + gp] = rec;
            }
        }
        __syncthreads();
        for (int b = t; b < nbuck; b += 256) {
            int c = scur[b];
            if (c >= 24) {
                int n = c < STAGE ? c : STAGE;
                int gp = atomicAdd(&gcur[b], n);
                int* rg = recs + (size_t)b * BUCKCAP + gp;
                for (int k = 0; k < n; ++k) rg[k] = stage[b][k];
                scur[b] = 0;
            }
        }
        __syncthreads();
    }
    for (int b = t; b < nbuck; b += 256) {
        int c = scur[b];
        if (c > 0) {
            int n = c < STAGE ? c : STAGE;
            int gp = atomicAdd(&gcur[b], n);
            int* rg = recs + (size_t)b * BUCKCAP + gp;
            for (int k = 0; k < n; ++k) rg[k] = stage[b][k];
        }
    }
}

// ---- pass B: one block per bucket; build ELL slice (L2-resident) + cnt -----
__global__ __launch_bounds__(256) void k_build(const int* __restrict__ recs,
                                               const int* __restrict__ gcur,
                                               int* __restrict__ ell,
                                               int* __restrict__ cnt, int N) {
    __shared__ int lcnt[256];
    int b = blockIdx.x;
    int t = threadIdx.x;
    lcnt[t] = 0;
    __syncthreads();
    int n = gcur[b]; if (n > BUCKCAP) n = BUCKCAP;
    const int* rp = recs + (size_t)b * BUCKCAP;
    int base = b << 8;
    for (int i = t; i < n; i += 256) {
        int rec = rp[i];
        int dl = rec & 255;
        int s = rec >> 8;
        int r = atomicAdd(&lcnt[dl], 1);
        if (r < MAXDEG) ell[(size_t)(base + dl) * MAXDEG + r] = s;
    }
    __syncthreads();
    int node = base + t;
    if (node < N) cnt[node] = lcnt[t];
}

// ---- prep: dinv + convert x -> planar g0 = dinv*x (fp16) -------------------
__global__ __launch_bounds__(256) void k_prep(const float4* __restrict__ x,
                                              const int* __restrict__ cnt,
                                              float* __restrict__ dinv,
                                              __half* __restrict__ g0, int N) {
    int t = threadIdx.x;
    int slot = t >> 5, lane = t & 31;
    int node = blockIdx.x * 8 + slot;
    if (node >= N) return;
    float sc = rsqrtf((float)cnt[node] + 1.0f);
    if (lane == 0) dinv[node] = sc;
    float4 v = x[(size_t)node * 32 + lane];     // features lane*4..+3
    float2 o;
    ((__half2*)&o)[0] = __float22half2_rn(make_float2(v.x * sc, v.y * sc));
    ((__half2*)&o)[1] = __float22half2_rn(make_float2(v.z * sc, v.w * sc));
    int p = lane >> 2, off = lane & 3;          // plane, float2-slot in row
    ((float2*)(g0 + (size_t)p * N * 16))[(size_t)node * 4 + off] = o;
}

// ---- aggregate (planar): block slice = b&7; 4 lanes/edge-row, 8 rows/iter --
__global__ __launch_bounds__(256) void k_agg(const __half* __restrict__ gin,
                                             const int* __restrict__ ell,
                                             const int* __restrict__ cnt,
                                             __half* __restrict__ gout, int N) {
    int t = threadIdx.x;
    int s = blockIdx.x & 7;                     // slice -> XCD (round-robin)
    int nodeBase = (blockIdx.x >> 3) * 32;
    int hw = t >> 5;                            // half-wave 0..7
    int lane = t & 31;
    int grp = lane >> 2, sub = lane & 3;

    const float2* pin = (const float2*)(gin + (size_t)s * N * 16);
    f32x2* pout = (f32x2*)(gout + (size_t)s * N * 16);

    for (int it = 0; it < 4; ++it) {
        int node = nodeBase + it * 8 + hw;
        if (node >= N) continue;

        float2 a0 = make_float2(0.f, 0.f), a1 = make_float2(0.f, 0.f);
        // self loop (group 0 only; other groups contribute 0)
        if (grp == 0) {
            float2 v = pin[(size_t)node * 4 + sub];
            a0 = __half22float2(((const __half2*)&v)[0]);
            a1 = __half22float2(((const __half2*)&v)[1]);
        }
        int deg = __builtin_nontemporal_load(cnt + node);
        if (deg > MAXDEG) deg = MAXDEG;
        const int* rowp = ell + (size_t)node * MAXDEG;
        for (int j = 0; j < deg; j += 8) {
            int e = j + grp;
            float2 v = make_float2(0.f, 0.f);
            if (e < deg) {
                int src = __builtin_nontemporal_load(rowp + e);
                v = pin[(size_t)src * 4 + sub];
            }
            float2 f0 = __half22float2(((const __half2*)&v)[0]);
            float2 f1 = __half22float2(((const __half2*)&v)[1]);
            a0.x += f0.x; a0.y += f0.y;
            a1.x += f1.x; a1.y += f1.y;
        }
        // reduce across the 8 groups (xor 4,8,16 stays inside 32-lane half)
#pragma unroll
        for (int m = 4; m <= 16; m <<= 1) {
            a0.x += __shfl_xor(a0.x, m);
            a0.y += __shfl_xor(a0.y, m);
            a1.x += __shfl_xor(a1.x, m);
            a1.y += __shfl_xor(a1.y, m);
        }
        if (grp == 0) {
            f32x2 o;
            __half2 h0 = __float22half2_rn(a0);
            __half2 h1 = __float22half2_rn(a1);
            o.x = *(const float*)&h0;
            o.y = *(const float*)&h1;
            __builtin_nontemporal_store(o, pout + (size_t)node * 4 + sub);
        }
    }
}

// ---- MFMA dense (layers 1,2): planar in/out, Wt from global ----------------
__global__ __launch_bounds__(256) void k_gemm_mfma(
    const __half* __restrict__ in,   // planar [8][N][16]
    const __half* __restrict__ Wt,   // [128 f][128 k] fp16 (= W^T), L1-hot
    const float* __restrict__ bias,
    const float* __restrict__ dinv,
    __half* __restrict__ outp,       // planar [8][N][16]
    int N)
{
    int t = threadIdx.x;
    int wave = t >> 6, lane = t & 63;
    int ln31 = lane & 31;
    int khalf = lane >> 5;
    int node = blockIdx.x * 128 + wave * 32 + ln31;
    bool valid = node < N;
    size_t n0 = (size_t)(valid ? node : 0);

    f16x8 bfrag[8];
#pragma unroll
    for (int kc = 0; kc < 8; ++kc)
        bfrag[kc] = *(const f16x8*)(in + (size_t)kc * N * 16 + n0 * 16 + khalf * 8);

    float scn = dinv[valid ? node : 0];
    const float4* Wg4 = (const float4*)Wt;

#pragma unroll
    for (int ft = 0; ft < 4; ++ft) {
        f32x16 acc = {0.f, 0.f, 0.f, 0.f, 0.f, 0.f, 0.f, 0.f,
                      0.f, 0.f, 0.f, 0.f, 0.f, 0.f, 0.f, 0.f};
#pragma unroll
        for (int kc = 0; kc < 8; ++kc) {
            int aidx = (ft * 32 + ln31) * 16 + kc * 2 + khalf;
            f16x8 afrag = *(const f16x8*)&Wg4[aidx];
            acc = __builtin_amdgcn_mfma_f32_32x32x16_f16(afrag, bfrag[kc], acc, 0, 0, 0);
        }
        if (valid) {
#pragma unroll
            for (int q = 0; q < 4; ++q) {
                int f = ft * 32 + q * 8 + khalf * 4;
                float4 bb = *(const float4*)&bias[f];
                float o0 = fmaxf(acc[q * 4 + 0] * scn + bb.x, 0.f) * scn;
                float o1 = fmaxf(acc[q * 4 + 1] * scn + bb.y, 0.f) * scn;
                float o2 = fmaxf(acc[q * 4 + 2] * scn + bb.z, 0.f) * scn;
                float o3 = fmaxf(acc[q * 4 + 3] * scn + bb.w, 0.f) * scn;
                float2 st;
                ((__half2*)&st)[0] = __float22half2_rn(make_float2(o0, o1));
                ((__half2*)&st)[1] = __float22half2_rn(make_float2(o2, o3));
                *(float2*)(outp + (size_t)(f >> 4) * N * 16 + n0 * 16 + (f & 15)) = st;
            }
        }
    }
}

// ---- layer 3: MFMA + fused mean-pool (planar in, no h write) ---------------
__global__ __launch_bounds__(256) void k_gemm_pool(
    const __half* __restrict__ in,   // planar [8][N][16]
    const __half* __restrict__ Wt,
    const float* __restrict__ bias,
    const float* __restrict__ dinv,
    const int* __restrict__ batch,   // sorted
    float* __restrict__ pooled,      // [128][128], pre-zeroed
    float* __restrict__ gcnt,        // [128], pre-zeroed
    int N)
{
    __shared__ float pp[8][128];
    __shared__ float pc[8];
    int t = threadIdx.x;
    int nb = blockIdx.x * 128;
    int lastn = nb + 127; if (lastn > N - 1) lastn = N - 1;
    int gs = batch[nb];
    int ge = batch[lastn];
    int ng = ge - gs + 1;

    for (int i = t; i < 8 * 128; i += 256) ((float*)pp)[i] = 0.f;
    if (t < 8) pc[t] = 0.f;
    __syncthreads();

    int wave = t >> 6, lane = t & 63;
    int ln31 = lane & 31;
    int khalf = lane >> 5;
    int node = nb + wave * 32 + ln31;
    bool valid = node < N;
    size_t n0 = (size_t)(valid ? node : 0);
    int g_lane = valid ? batch[node] : -1;

    f16x8 bfrag[8];
#pragma unroll
    for (int kc = 0; kc < 8; ++kc)
        bfrag[kc] = *(const f16x8*)(in + (size_t)kc * N * 16 + n0 * 16 + khalf * 8);

    float scn = dinv[valid ? node : 0];
    const float4* Wg4 = (const float4*)Wt;

    for (int gg = 0; gg < ng; ++gg) {
        float cv = (khalf == 0 && g_lane == gs + gg) ? 1.f : 0.f;
#pragma unroll
        for (int m = 1; m <= 16; m <<= 1) cv += __shfl_xor(cv, m);
        if (lane == 0 && cv != 0.f) {
            if (gg < 8) atomicAdd(&pc[gg], cv);
            else        atomicAdd(&gcnt[gs + gg], cv);
        }
    }

#pragma unroll
    for (int ft = 0; ft < 4; ++ft) {
        f32x16 acc = {0.f, 0.f, 0.f, 0.f, 0.f, 0.f, 0.f, 0.f,
                      0.f, 0.f, 0.f, 0.f, 0.f, 0.f, 0.f, 0.f};
#pragma unroll
        for (int kc = 0; kc < 8; ++kc) {
            int aidx = (ft * 32 + ln31) * 16 + kc * 2 + khalf;
            f16x8 afrag = *(const f16x8*)&Wg4[aidx];
            acc = __builtin_amdgcn_mfma_f32_32x32x16_f16(afrag, bfrag[kc], acc, 0, 0, 0);
        }
#pragma unroll
        for (int q = 0; q < 4; ++q) {
            int f = ft * 32 + q * 8 + khalf * 4;
            float4 bb = *(const float4*)&bias[f];
            float h0 = fmaxf(acc[q * 4 + 0] * scn + bb.x, 0.f);
            float h1 = fmaxf(acc[q * 4 + 1] * scn + bb.y, 0.f);
            float h2 = fmaxf(acc[q * 4 + 2] * scn + bb.z, 0.f);
            float h3 = fmaxf(acc[q * 4 + 3] * scn + bb.w, 0.f);
            for (int gg = 0; gg < ng; ++gg) {
                int g = gs + gg;
                bool m = (g_lane == g);
                float v0 = m ? h0 : 0.f, v1 = m ? h1 : 0.f;
                float v2 = m ? h2 : 0.f, v3 = m ? h3 : 0.f;
#pragma unroll
                for (int mm = 1; mm <= 16; mm <<= 1) {
                    v0 += __shfl_xor(v0, mm);
                    v1 += __shfl_xor(v1, mm);
                    v2 += __shfl_xor(v2, mm);
                    v3 += __shfl_xor(v3, mm);
                }
                if (ln31 == 0) {
                    if (gg < 8) {
                        if (v0 != 0.f) atomicAdd(&pp[gg][f + 0], v0);
                        if (v1 != 0.f) atomicAdd(&pp[gg][f + 1], v1);
                        if (v2 != 0.f) atomicAdd(&pp[gg][f + 2], v2);
                        if (v3 != 0.f) atomicAdd(&pp[gg][f + 3], v3);
                    } else {
                        if (v0 != 0.f) atomicAdd(&pooled[g * 128 + f + 0], v0);
                        if (v1 != 0.f) atomicAdd(&pooled[g * 128 + f + 1], v1);
                        if (v2 != 0.f) atomicAdd(&pooled[g * 128 + f + 2], v2);
                        if (v3 != 0.f) atomicAdd(&pooled[g * 128 + f + 3], v3);
                    }
                }
            }
        }
    }
    __syncthreads();
    int ngc = ng < 8 ? ng : 8;
    if (t < 128) {
        for (int gg = 0; gg < ngc; ++gg) {
            float v = pp[gg][t];
            if (v != 0.f) atomicAdd(&pooled[(gs + gg) * 128 + t], v);
        }
    }
    if (t == 0) {
        for (int gg = 0; gg < ngc; ++gg)
            if (pc[gg] != 0.f) atomicAdd(&gcnt[gs + gg], pc[gg]);
    }
}

// ---- FFN: out[g] = relu(pooled_mean @ Wf1 + bf1) @ Wf2 + bf2 ---------------
__global__ __launch_bounds__(128) void k_ffn(const float* __restrict__ pooled,
                                             const float* __restrict__ gcnt,
                                             const float* __restrict__ Wf1,
                                             const float* __restrict__ bf1,
                                             const float* __restrict__ Wf2,
                                             const float* __restrict__ bf2,
                                             float* __restrict__ out, int C) {
    __shared__ float pl[128];
    __shared__ float hid[128];
    int g = blockIdx.x;
    int t = threadIdx.x;
    float invc = 1.0f / fmaxf(gcnt[g], 1.0f);
    pl[t] = pooled[g * 128 + t] * invc;
    __syncthreads();
    float s = bf1[t];
    for (int k = 0; k < 128; ++k) s += pl[k] * Wf1[k * 128 + t];
    hid[t] = fmaxf(s, 0.f);
    __syncthreads();
    if (t < C) {
        float o = bf2[t];
        for (int f = 0; f < 128; ++f) o += hid[f] * Wf2[f * C + t];
        out[g * C + t] = o;
    }
}

extern "C" void kernel_launch(void* const* d_in, const int* in_sizes, int n_in,
                              void* d_out, int out_size, void* d_ws, size_t ws_size,
                              hipStream_t stream) {
    const float* x   = (const float*)d_in[0];
    const int*   ei  = (const int*)d_in[1];
    const int*   bat = (const int*)d_in[2];
    const float* W1  = (const float*)d_in[3];
    const float* b1  = (const float*)d_in[4];
    const float* W2  = (const float*)d_in[5];
    const float* b2  = (const float*)d_in[6];
    const float* W3  = (const float*)d_in[7];
    const float* b3  = (const float*)d_in[8];
    const float* Wf1 = (const float*)d_in[9];
    const float* bf1 = (const float*)d_in[10];
    const float* Wf2 = (const float*)d_in[11];
    const float* bf2 = (const float*)d_in[12];
    float* out = (float*)d_out;

    int N = in_sizes[2];
    int E = in_sizes[1] / 2;
    int C = in_sizes[12];
    const int* row  = ei;
    const int* colv = ei + E;

    int nbuck = (N + 255) / 256;
    int Npad  = nbuck * 256;

    auto align256 = [](char* p) {
        return (char*)(((uintptr_t)p + 255) & ~(uintptr_t)255);
    };
    char* w = (char*)d_ws;
    __half* bufX = (__half*)w; w += (size_t)N * 128 * 2; w = align256(w);
    __half* bufY = (__half*)w; w += (size_t)N * 128 * 2; w = align256(w);
    __half* bufZ = (__half*)w; w += (size_t)N * 128 * 2; w = align256(w);
    int* ell     = (int*)w;   w += (size_t)Npad * MAXDEG * 4; w = align256(w);
    int* recs    = (int*)w;   w += (size_t)nbuck * BUCKCAP * 4; w = align256(w);
    int* cnt     = (int*)w;   w += (size_t)Npad * 4;    w = align256(w);
    float* dinv  = (float*)w; w += (size_t)N * 4;       w = align256(w);
    int* gcur    = (int*)w;   w += NBUCKMAX * 4;        w = align256(w);
    __half* Wt1  = (__half*)w; w += 128 * 128 * 2;      w = align256(w);
    __half* Wt2  = (__half*)w; w += 128 * 128 * 2;      w = align256(w);
    __half* Wt3  = (__half*)w; w += 128 * 128 * 2;      w = align256(w);
    float* pooled= (float*)w;  w += 128 * 128 * 4;      w = align256(w);
    float* gcnt  = (float*)w;  w += 128 * 4;

    int nnode8 = (N + 7) / 8;
    int nagg   = 8 * ((N + 31) / 32);
    int ngemm  = (N + 127) / 128;

    k_cvtw  <<<64, 256, 0, stream>>>(W1, W2, W3, Wt1, Wt2, Wt3, pooled, gcnt, gcur);
    k_bucket<<<256, 256, 0, stream>>>(row, colv, E, nbuck, gcur, recs);
    k_build <<<nbuck, 256, 0, stream>>>(recs, gcur, ell, cnt, N);
    k_prep  <<<nnode8, 256, 0, stream>>>((const float4*)x, cnt, dinv, bufX, N);

    // layer 1: bufX -> agg bufZ -> gemm bufY (scaled)
    k_agg <<<nagg, 256, 0, stream>>>(bufX, ell, cnt, bufZ, N);
    k_gemm_mfma<<<ngemm, 256, 0, stream>>>(bufZ, Wt1, b1, dinv, bufY, N);
    // layer 2: bufY -> agg bufZ -> gemm bufX (scaled)
    k_agg <<<nagg, 256, 0, stream>>>(bufY, ell, cnt, bufZ, N);
    k_gemm_mfma<<<ngemm, 256, 0, stream>>>(bufZ, Wt2, b2, dinv, bufX, N);
    // layer 3: bufX -> agg bufZ -> gemm+pool (no h write)
    k_agg <<<nagg, 256, 0, stream>>>(bufX, ell, cnt, bufZ, N);
    k_gemm_pool<<<ngemm, 256, 0, stream>>>(bufZ, Wt3, b3, dinv, bat,
                                           pooled, gcnt, N);

    k_ffn <<<128, 128, 0, stream>>>(pooled, gcnt, Wf1, bf1, Wf2, bf2, out, C);
}

// Round 14
// 272.617 us; speedup vs baseline: 2.6763x; 2.6763x over previous
//
#include <hip/hip_runtime.h>
#include <hip/hip_fp16.h>

// ---------------------------------------------------------------------------
// GCN 3-layer forward — fp8 gather edition.
//   Stored per layer: s_l = 16 * dinv * h_l  in fp8 e4m3 [N][128] (128B/row).
//   agg[dst] = sum_src s[src] + s[dst]  (fp32 accum) -> bufZ fp16 [N][128].
//   GEMM (MFMA f16, Wt fp16 direct-from-global): h = relu(dinv*(aggW)/16 + b);
//   layers 1,2 store fp8(16*dinv*h); layer 3 fused with mean-pool (fp32).
// Adjacency: two-pass binned ELL build (verified r6 config).
// ---------------------------------------------------------------------------

#define MAXDEG 64
#define NBUCKMAX 512
#define STAGE 32
#define BUCKCAP 8192
#define FP8_S 16.0f
#define FP8_INVS 0.0625f

typedef _Float16 f16x8 __attribute__((ext_vector_type(8)));
typedef float f32x16 __attribute__((ext_vector_type(16)));
typedef float f32x2v __attribute__((ext_vector_type(2)));

__device__ __forceinline__ void fp8x4_acc(unsigned v, float2& a0, float2& a1) {
    f32x2v lo = __builtin_amdgcn_cvt_pk_f32_fp8((int)v, false);
    f32x2v hi = __builtin_amdgcn_cvt_pk_f32_fp8((int)v, true);
    a0.x += lo[0]; a0.y += lo[1];
    a1.x += hi[0]; a1.y += hi[1];
}

__device__ __forceinline__ unsigned fp8x4_pack(float a, float b, float c, float d) {
    int r = 0;
    r = __builtin_amdgcn_cvt_pk_fp8_f32(a, b, r, false);
    r = __builtin_amdgcn_cvt_pk_fp8_f32(c, d, r, true);
    return (unsigned)r;
}

// ---- weights fp32->fp16 TRANSPOSED (Wt[f][k] = W[k][f]) + zero-inits -------
__global__ void k_cvtw(const float* __restrict__ W1, const float* __restrict__ W2,
                       const float* __restrict__ W3, __half* __restrict__ o1,
                       __half* __restrict__ o2, __half* __restrict__ o3,
                       float* __restrict__ pooled, float* __restrict__ gcnt,
                       int* __restrict__ gcur) {
    int i = blockIdx.x * blockDim.x + threadIdx.x;   // 16384, i = f*128+k
    int src = ((i & 127) << 7) + (i >> 7);           // W[k][f]
    o1[i] = __float2half_rn(W1[src]);
    o2[i] = __float2half_rn(W2[src]);
    o3[i] = __float2half_rn(W3[src]);
    pooled[i] = 0.f;
    if (i < 128) gcnt[i] = 0.f;
    if (i < NBUCKMAX) gcur[i] = 0;
}

// ---- pass A: bucket edges into per-bucket record regions -------------------
__global__ __launch_bounds__(256) void k_bucket(const int* __restrict__ row,
                                                const int* __restrict__ col,
                                                int E, int nbuck,
                                                int* __restrict__ gcur,
                                                int* __restrict__ recs) {
    __shared__ int stage[NBUCKMAX][STAGE];   // 64 KB
    __shared__ int scur[NBUCKMAX];
    int t = threadIdx.x;
    for (int i = t; i < NBUCKMAX; i += 256) scur[i] = 0;
    __syncthreads();

    int nblk = gridDim.x;
    int chunk = (((E + nblk - 1) / nblk) + 255) & ~255;
    int e0 = blockIdx.x * chunk;
    int e1 = e0 + chunk; if (e1 > E) e1 = E;

    for (int base = e0; base < e1; base += 256) {
        int e = base + t;
        if (e < e1) {
            int s = row[e], d = col[e];
            int b = d >> 8;
            int rec = (s << 8) | (d & 255);
            int slot = atomicAdd(&scur[b], 1);
            if (slot < STAGE) {
                stage[b][slot] = rec;
            } else {
                int gp = atomicAdd(&gcur[b], 1);
                if (gp < BUCKCAP) recs[(size_t)b * BUCKCAP + gp] = rec;
            }
        }
        __syncthreads();
        for (int b = t; b < nbuck; b += 256) {
            int c = scur[b];
            if (c >= 24) {
                int n = c < STAGE ? c : STAGE;
                int gp = atomicAdd(&gcur[b], n);
                int* rg = recs + (size_t)b * BUCKCAP + gp;
                for (int k = 0; k < n; ++k) rg[k] = stage[b][k];
                scur[b] = 0;
            }
        }
        __syncthreads();
    }
    for (int b = t; b < nbuck; b += 256) {
        int c = scur[b];
        if (c > 0) {
            int n = c < STAGE ? c : STAGE;
            int gp = atomicAdd(&gcur[b], n);
            int* rg = recs + (size_t)b * BUCKCAP + gp;
            for (int k = 0; k < n; ++k) rg[k] = stage[b][k];
        }
    }
}

// ---- pass B: one block per bucket; build ELL slice (L2-resident) + cnt -----
__global__ __launch_bounds__(256) void k_build(const int* __restrict__ recs,
                                               const int* __restrict__ gcur,
                                               int* __restrict__ ell,
                                               int* __restrict__ cnt, int N) {
    __shared__ int lcnt[256];
    int b = blockIdx.x;
    int t = threadIdx.x;
    lcnt[t] = 0;
    __syncthreads();
    int n = gcur[b]; if (n > BUCKCAP) n = BUCKCAP;
    const int* rp = recs + (size_t)b * BUCKCAP;
    int base = b << 8;
    for (int i = t; i < n; i += 256) {
        int rec = rp[i];
        int dl = rec & 255;
        int s = rec >> 8;
        int r = atomicAdd(&lcnt[dl], 1);
        if (r < MAXDEG) ell[(size_t)(base + dl) * MAXDEG + r] = s;
    }
    __syncthreads();
    int node = base + t;
    if (node < N) cnt[node] = lcnt[t];
}

// ---- prep: dinv + convert x -> s0 = 16*dinv*x (fp8 [N][32] uints) ----------
__global__ __launch_bounds__(256) void k_prep(const float4* __restrict__ x,
                                              const int* __restrict__ cnt,
                                              float* __restrict__ dinv,
                                              unsigned* __restrict__ g0, int N) {
    int t = threadIdx.x;
    int slot = t >> 5, lane = t & 31;
    int node = blockIdx.x * 8 + slot;
    if (node >= N) return;
    float sc = rsqrtf((float)cnt[node] + 1.0f);
    if (lane == 0) dinv[node] = sc;
    float m = sc * FP8_S;
    float4 v = x[(size_t)node * 32 + lane];     // features lane*4..+3
    g0[(size_t)node * 32 + lane] = fp8x4_pack(v.x * m, v.y * m, v.z * m, v.w * m);
}

// ---- aggregate: half-wave per node, 4B(fp8x4)/lane, 8 rows in flight -------
__global__ __launch_bounds__(256) void k_agg(const unsigned* __restrict__ gin,
                                             const int* __restrict__ ell,
                                             const int* __restrict__ cnt,
                                             float2* __restrict__ gout, int N) {
    int t = threadIdx.x;
    int slot = t >> 5;        // 0..7
    int lane = t & 31;
    int node = blockIdx.x * 8 + slot;
    if (node >= N) return;

    float2 a0 = make_float2(0.f, 0.f), a1 = make_float2(0.f, 0.f);
    fp8x4_acc(gin[(size_t)node * 32 + lane], a0, a1);   // self loop

    int deg = cnt[node]; if (deg > MAXDEG) deg = MAXDEG;
    const int* rowp = ell + (size_t)node * MAXDEG;
    int j = 0;
    for (; j + 7 < deg; j += 8) {
        int4 sa = *(const int4*)(rowp + j);
        int4 sb = *(const int4*)(rowp + j + 4);
        unsigned v0 = gin[(size_t)sa.x * 32 + lane];
        unsigned v1 = gin[(size_t)sa.y * 32 + lane];
        unsigned v2 = gin[(size_t)sa.z * 32 + lane];
        unsigned v3 = gin[(size_t)sa.w * 32 + lane];
        unsigned v4 = gin[(size_t)sb.x * 32 + lane];
        unsigned v5 = gin[(size_t)sb.y * 32 + lane];
        unsigned v6 = gin[(size_t)sb.z * 32 + lane];
        unsigned v7 = gin[(size_t)sb.w * 32 + lane];
        fp8x4_acc(v0, a0, a1); fp8x4_acc(v1, a0, a1);
        fp8x4_acc(v2, a0, a1); fp8x4_acc(v3, a0, a1);
        fp8x4_acc(v4, a0, a1); fp8x4_acc(v5, a0, a1);
        fp8x4_acc(v6, a0, a1); fp8x4_acc(v7, a0, a1);
    }
    for (; j + 3 < deg; j += 4) {
        int4 s4 = *(const int4*)(rowp + j);
        unsigned v0 = gin[(size_t)s4.x * 32 + lane];
        unsigned v1 = gin[(size_t)s4.y * 32 + lane];
        unsigned v2 = gin[(size_t)s4.z * 32 + lane];
        unsigned v3 = gin[(size_t)s4.w * 32 + lane];
        fp8x4_acc(v0, a0, a1); fp8x4_acc(v1, a0, a1);
        fp8x4_acc(v2, a0, a1); fp8x4_acc(v3, a0, a1);
    }
    for (; j < deg; ++j) {
        fp8x4_acc(gin[(size_t)rowp[j] * 32 + lane], a0, a1);
    }
    float2 o;   // 4 halfs: features lane*4..+3 (scaled by 16, fp16 holds it)
    ((__half2*)&o)[0] = __float22half2_rn(a0);
    ((__half2*)&o)[1] = __float22half2_rn(a1);
    gout[(size_t)node * 32 + lane] = o;
}

// ---- MFMA dense (layers 1,2): bufZ fp16 in, fp8(16*dinv*h) out -------------
__global__ __launch_bounds__(256) void k_gemm_mfma(
    const __half* __restrict__ in,   // [N][128] fp16 (16*agg)
    const __half* __restrict__ Wt,   // [128 f][128 k] fp16 (= W^T), L1-hot
    const float* __restrict__ bias,
    const float* __restrict__ dinv,
    unsigned* __restrict__ outp,     // fp8 [N][32] uints
    int N)
{
    int t = threadIdx.x;
    int wave = t >> 6, lane = t & 63;
    int ln31 = lane & 31;
    int khalf = lane >> 5;                     // 0/1
    int node = blockIdx.x * 128 + wave * 32 + ln31;
    bool valid = node < N;
    size_t nrow = (size_t)(valid ? node : 0) * 128;

    f16x8 bfrag[8];
    const f16x8* inrow = (const f16x8*)(in + nrow);
#pragma unroll
    for (int kc = 0; kc < 8; ++kc) bfrag[kc] = inrow[kc * 2 + khalf];

    float scn = dinv[valid ? node : 0];
    float epi = scn * FP8_INVS;                // undo 16x storage scale
    float sto = scn * FP8_S;                   // re-apply for next layer
    const float4* Wg4 = (const float4*)Wt;

#pragma unroll
    for (int ft = 0; ft < 4; ++ft) {
        f32x16 acc = {0.f, 0.f, 0.f, 0.f, 0.f, 0.f, 0.f, 0.f,
                      0.f, 0.f, 0.f, 0.f, 0.f, 0.f, 0.f, 0.f};
#pragma unroll
        for (int kc = 0; kc < 8; ++kc) {
            int aidx = (ft * 32 + ln31) * 16 + kc * 2 + khalf;
            f16x8 afrag = *(const f16x8*)&Wg4[aidx];
            acc = __builtin_amdgcn_mfma_f32_32x32x16_f16(afrag, bfrag[kc], acc, 0, 0, 0);
        }
        if (valid) {
#pragma unroll
            for (int q = 0; q < 4; ++q) {
                int f = ft * 32 + q * 8 + khalf * 4;
                float4 bb = *(const float4*)&bias[f];
                float o0 = fmaxf(acc[q * 4 + 0] * epi + bb.x, 0.f);
                float o1 = fmaxf(acc[q * 4 + 1] * epi + bb.y, 0.f);
                float o2 = fmaxf(acc[q * 4 + 2] * epi + bb.z, 0.f);
                float o3 = fmaxf(acc[q * 4 + 3] * epi + bb.w, 0.f);
                outp[(size_t)node * 32 + (f >> 2)] =
                    fp8x4_pack(o0 * sto, o1 * sto, o2 * sto, o3 * sto);
            }
        }
    }
}

// ---- layer 3: MFMA + fused mean-pool (fp16 in, fp32 pool, no h write) ------
__global__ __launch_bounds__(256) void k_gemm_pool(
    const __half* __restrict__ in,   // [N][128] fp16 (16*agg)
    const __half* __restrict__ Wt,
    const float* __restrict__ bias,
    const float* __restrict__ dinv,
    const int* __restrict__ batch,   // sorted
    float* __restrict__ pooled,      // [128][128], pre-zeroed
    float* __restrict__ gcnt,        // [128], pre-zeroed
    int N)
{
    __shared__ float pp[8][128];
    __shared__ float pc[8];
    int t = threadIdx.x;
    int nb = blockIdx.x * 128;
    int lastn = nb + 127; if (lastn > N - 1) lastn = N - 1;
    int gs = batch[nb];
    int ge = batch[lastn];
    int ng = ge - gs + 1;

    for (int i = t; i < 8 * 128; i += 256) ((float*)pp)[i] = 0.f;
    if (t < 8) pc[t] = 0.f;
    __syncthreads();

    int wave = t >> 6, lane = t & 63;
    int ln31 = lane & 31;
    int khalf = lane >> 5;
    int node = nb + wave * 32 + ln31;
    bool valid = node < N;
    size_t nrow = (size_t)(valid ? node : 0) * 128;
    int g_lane = valid ? batch[node] : -1;

    f16x8 bfrag[8];
    const f16x8* inrow = (const f16x8*)(in + nrow);
#pragma unroll
    for (int kc = 0; kc < 8; ++kc) bfrag[kc] = inrow[kc * 2 + khalf];

    float scn = dinv[valid ? node : 0];
    float epi = scn * FP8_INVS;
    const float4* Wg4 = (const float4*)Wt;

    for (int gg = 0; gg < ng; ++gg) {
        float cv = (khalf == 0 && g_lane == gs + gg) ? 1.f : 0.f;
#pragma unroll
        for (int m = 1; m <= 16; m <<= 1) cv += __shfl_xor(cv, m);
        if (lane == 0 && cv != 0.f) {
            if (gg < 8) atomicAdd(&pc[gg], cv);
            else        atomicAdd(&gcnt[gs + gg], cv);
        }
    }

#pragma unroll
    for (int ft = 0; ft < 4; ++ft) {
        f32x16 acc = {0.f, 0.f, 0.f, 0.f, 0.f, 0.f, 0.f, 0.f,
                      0.f, 0.f, 0.f, 0.f, 0.f, 0.f, 0.f, 0.f};
#pragma unroll
        for (int kc = 0; kc < 8; ++kc) {
            int aidx = (ft * 32 + ln31) * 16 + kc * 2 + khalf;
            f16x8 afrag = *(const f16x8*)&Wg4[aidx];
            acc = __builtin_amdgcn_mfma_f32_32x32x16_f16(afrag, bfrag[kc], acc, 0, 0, 0);
        }
#pragma unroll
        for (int q = 0; q < 4; ++q) {
            int f = ft * 32 + q * 8 + khalf * 4;
            float4 bb = *(const float4*)&bias[f];
            float h0 = fmaxf(acc[q * 4 + 0] * epi + bb.x, 0.f);
            float h1 = fmaxf(acc[q * 4 + 1] * epi + bb.y, 0.f);
            float h2 = fmaxf(acc[q * 4 + 2] * epi + bb.z, 0.f);
            float h3 = fmaxf(acc[q * 4 + 3] * epi + bb.w, 0.f);
            for (int gg = 0; gg < ng; ++gg) {
                int g = gs + gg;
                bool m = (g_lane == g);
                float v0 = m ? h0 : 0.f, v1 = m ? h1 : 0.f;
                float v2 = m ? h2 : 0.f, v3 = m ? h3 : 0.f;
#pragma unroll
                for (int mm = 1; mm <= 16; mm <<= 1) {
                    v0 += __shfl_xor(v0, mm);
                    v1 += __shfl_xor(v1, mm);
                    v2 += __shfl_xor(v2, mm);
                    v3 += __shfl_xor(v3, mm);
                }
                if (ln31 == 0) {
                    if (gg < 8) {
                        if (v0 != 0.f) atomicAdd(&pp[gg][f + 0], v0);
                        if (v1 != 0.f) atomicAdd(&pp[gg][f + 1], v1);
                        if (v2 != 0.f) atomicAdd(&pp[gg][f + 2], v2);
                        if (v3 != 0.f) atomicAdd(&pp[gg][f + 3], v3);
                    } else {
                        if (v0 != 0.f) atomicAdd(&pooled[g * 128 + f + 0], v0);
                        if (v1 != 0.f) atomicAdd(&pooled[g * 128 + f + 1], v1);
                        if (v2 != 0.f) atomicAdd(&pooled[g * 128 + f + 2], v2);
                        if (v3 != 0.f) atomicAdd(&pooled[g * 128 + f + 3], v3);
                    }
                }
            }
        }
    }
    __syncthreads();
    int ngc = ng < 8 ? ng : 8;
    if (t < 128) {
        for (int gg = 0; gg < ngc; ++gg) {
            float v = pp[gg][t];
            if (v != 0.f) atomicAdd(&pooled[(gs + gg) * 128 + t], v);
        }
    }
    if (t == 0) {
        for (int gg = 0; gg < ngc; ++gg)
            if (pc[gg] != 0.f) atomicAdd(&gcnt[gs + gg], pc[gg]);
    }
}

// ---- FFN: out[g] = relu(pooled_mean @ Wf1 + bf1) @ Wf2 + bf2 ---------------
__global__ __launch_bounds__(128) void k_ffn(const float* __restrict__ pooled,
                                             const float* __restrict__ gcnt,
                                             const float* __restrict__ Wf1,
                                             const float* __restrict__ bf1,
                                             const float* __restrict__ Wf2,
                                             const float* __restrict__ bf2,
                                             float* __restrict__ out, int C) {
    __shared__ float pl[128];
    __shared__ float hid[128];
    int g = blockIdx.x;
    int t = threadIdx.x;
    float invc = 1.0f / fmaxf(gcnt[g], 1.0f);
    pl[t] = pooled[g * 128 + t] * invc;
    __syncthreads();
    float s = bf1[t];
    for (int k = 0; k < 128; ++k) s += pl[k] * Wf1[k * 128 + t];
    hid[t] = fmaxf(s, 0.f);
    __syncthreads();
    if (t < C) {
        float o = bf2[t];
        for (int f = 0; f < 128; ++f) o += hid[f] * Wf2[f * C + t];
        out[g * C + t] = o;
    }
}

extern "C" void kernel_launch(void* const* d_in, const int* in_sizes, int n_in,
                              void* d_out, int out_size, void* d_ws, size_t ws_size,
                              hipStream_t stream) {
    const float* x   = (const float*)d_in[0];
    const int*   ei  = (const int*)d_in[1];
    const int*   bat = (const int*)d_in[2];
    const float* W1  = (const float*)d_in[3];
    const float* b1  = (const float*)d_in[4];
    const float* W2  = (const float*)d_in[5];
    const float* b2  = (const float*)d_in[6];
    const float* W3  = (const float*)d_in[7];
    const float* b3  = (const float*)d_in[8];
    const float* Wf1 = (const float*)d_in[9];
    const float* bf1 = (const float*)d_in[10];
    const float* Wf2 = (const float*)d_in[11];
    const float* bf2 = (const float*)d_in[12];
    float* out = (float*)d_out;

    int N = in_sizes[2];
    int E = in_sizes[1] / 2;
    int C = in_sizes[12];
    const int* row  = ei;
    const int* colv = ei + E;

    int nbuck = (N + 255) / 256;
    int Npad  = nbuck * 256;

    auto align256 = [](char* p) {
        return (char*)(((uintptr_t)p + 255) & ~(uintptr_t)255);
    };
    char* w = (char*)d_ws;
    unsigned* bufX8 = (unsigned*)w; w += (size_t)N * 128;   w = align256(w);
    unsigned* bufY8 = (unsigned*)w; w += (size_t)N * 128;   w = align256(w);
    __half* bufZ = (__half*)w; w += (size_t)N * 128 * 2;    w = align256(w);
    int* ell     = (int*)w;   w += (size_t)Npad * MAXDEG * 4; w = align256(w);
    int* recs    = (int*)w;   w += (size_t)nbuck * BUCKCAP * 4; w = align256(w);
    int* cnt     = (int*)w;   w += (size_t)Npad * 4;    w = align256(w);
    float* dinv  = (float*)w; w += (size_t)N * 4;       w = align256(w);
    int* gcur    = (int*)w;   w += NBUCKMAX * 4;        w = align256(w);
    __half* Wt1  = (__half*)w; w += 128 * 128 * 2;      w = align256(w);
    __half* Wt2  = (__half*)w; w += 128 * 128 * 2;      w = align256(w);
    __half* Wt3  = (__half*)w; w += 128 * 128 * 2;      w = align256(w);
    float* pooled= (float*)w;  w += 128 * 128 * 4;      w = align256(w);
    float* gcnt  = (float*)w;  w += 128 * 4;

    int nnode8 = (N + 7) / 8;
    int ngemm  = (N + 127) / 128;

    k_cvtw  <<<64, 256, 0, stream>>>(W1, W2, W3, Wt1, Wt2, Wt3, pooled, gcnt, gcur);
    k_bucket<<<256, 256, 0, stream>>>(row, colv, E, nbuck, gcur, recs);
    k_build <<<nbuck, 256, 0, stream>>>(recs, gcur, ell, cnt, N);
    k_prep  <<<nnode8, 256, 0, stream>>>((const float4*)x, cnt, dinv, bufX8, N);

    // layer 1: bufX8 -> agg bufZ -> gemm bufY8 (fp8, 16*dinv*h)
    k_agg <<<nnode8, 256, 0, stream>>>(bufX8, ell, cnt, (float2*)bufZ, N);
    k_gemm_mfma<<<ngemm, 256, 0, stream>>>(bufZ, Wt1, b1, dinv, bufY8, N);
    // layer 2: bufY8 -> agg bufZ -> gemm bufX8
    k_agg <<<nnode8, 256, 0, stream>>>(bufY8, ell, cnt, (float2*)bufZ, N);
    k_gemm_mfma<<<ngemm, 256, 0, stream>>>(bufZ, Wt2, b2, dinv, bufX8, N);
    // layer 3: bufX8 -> agg bufZ -> gemm+pool (no h write)
    k_agg <<<nnode8, 256, 0, stream>>>(bufX8, ell, cnt, (float2*)bufZ, N);
    k_gemm_pool<<<ngemm, 256, 0, stream>>>(bufZ, Wt3, b3, dinv, bat,
                                           pooled, gcnt, N);

    k_ffn <<<128, 128, 0, stream>>>(pooled, gcnt, Wf1, bf1, Wf2, bf2, out, C);
}

// Round 16
// 271.330 us; speedup vs baseline: 2.6890x; 1.0047x over previous
//
#include <hip/hip_runtime.h>
#include <hip/hip_fp16.h>

// ---------------------------------------------------------------------------
// GCN 3-layer forward — fp8 gather edition (r14 verified) + bucket grid 512.
//   Stored per layer: s_l = 16 * dinv * h_l  in fp8 e4m3 [N][128] (128B/row).
//   agg[dst] = sum_src s[src] + s[dst]  (fp32 accum) -> bufZ fp16 [N][128].
//   GEMM (MFMA f16, Wt fp16 direct-from-global): h = relu(dinv*(aggW)/16 + b);
//   layers 1,2 store fp8(16*dinv*h); layer 3 fused with mean-pool (fp32).
// Adjacency: two-pass binned ELL build; pass A now grid=512 (all CUs busy).
// ---------------------------------------------------------------------------

#define MAXDEG 64
#define NBUCKMAX 512
#define STAGE 32
#define BUCKCAP 8192
#define FP8_S 16.0f
#define FP8_INVS 0.0625f

typedef _Float16 f16x8 __attribute__((ext_vector_type(8)));
typedef float f32x16 __attribute__((ext_vector_type(16)));
typedef float f32x2v __attribute__((ext_vector_type(2)));

__device__ __forceinline__ void fp8x4_acc(unsigned v, float2& a0, float2& a1) {
    f32x2v lo = __builtin_amdgcn_cvt_pk_f32_fp8((int)v, false);
    f32x2v hi = __builtin_amdgcn_cvt_pk_f32_fp8((int)v, true);
    a0.x += lo[0]; a0.y += lo[1];
    a1.x += hi[0]; a1.y += hi[1];
}

__device__ __forceinline__ unsigned fp8x4_pack(float a, float b, float c, float d) {
    int r = 0;
    r = __builtin_amdgcn_cvt_pk_fp8_f32(a, b, r, false);
    r = __builtin_amdgcn_cvt_pk_fp8_f32(c, d, r, true);
    return (unsigned)r;
}

// ---- weights fp32->fp16 TRANSPOSED (Wt[f][k] = W[k][f]) + zero-inits -------
__global__ void k_cvtw(const float* __restrict__ W1, const float* __restrict__ W2,
                       const float* __restrict__ W3, __half* __restrict__ o1,
                       __half* __restrict__ o2, __half* __restrict__ o3,
                       float* __restrict__ pooled, float* __restrict__ gcnt,
                       int* __restrict__ gcur) {
    int i = blockIdx.x * blockDim.x + threadIdx.x;   // 16384, i = f*128+k
    int src = ((i & 127) << 7) + (i >> 7);           // W[k][f]
    o1[i] = __float2half_rn(W1[src]);
    o2[i] = __float2half_rn(W2[src]);
    o3[i] = __float2half_rn(W3[src]);
    pooled[i] = 0.f;
    if (i < 128) gcnt[i] = 0.f;
    if (i < NBUCKMAX) gcur[i] = 0;
}

// ---- pass A: bucket edges into per-bucket record regions -------------------
__global__ __launch_bounds__(256) void k_bucket(const int* __restrict__ row,
                                                const int* __restrict__ col,
                                                int E, int nbuck,
                                                int* __restrict__ gcur,
                                                int* __restrict__ recs) {
    __shared__ int stage[NBUCKMAX][STAGE];   // 64 KB
    __shared__ int scur[NBUCKMAX];
    int t = threadIdx.x;
    for (int i = t; i < NBUCKMAX; i += 256) scur[i] = 0;
    __syncthreads();

    int nblk = gridDim.x;
    int chunk = (((E + nblk - 1) / nblk) + 255) & ~255;
    int e0 = blockIdx.x * chunk;
    int e1 = e0 + chunk; if (e1 > E) e1 = E;

    for (int base = e0; base < e1; base += 256) {
        int e = base + t;
        if (e < e1) {
            int s = row[e], d = col[e];
            int b = d >> 8;
            int rec = (s << 8) | (d & 255);
            int slot = atomicAdd(&scur[b], 1);
            if (slot < STAGE) {
                stage[b][slot] = rec;
            } else {
                int gp = atomicAdd(&gcur[b], 1);
                if (gp < BUCKCAP) recs[(size_t)b * BUCKCAP + gp] = rec;
            }
        }
        __syncthreads();
        for (int b = t; b < nbuck; b += 256) {
            int c = scur[b];
            if (c >= 24) {
                int n = c < STAGE ? c : STAGE;
                int gp = atomicAdd(&gcur[b], n);
                int* rg = recs + (size_t)b * BUCKCAP + gp;
                for (int k = 0; k < n; ++k) rg[k] = stage[b][k];
                scur[b] = 0;
            }
        }
        __syncthreads();
    }
    for (int b = t; b < nbuck; b += 256) {
        int c = scur[b];
        if (c > 0) {
            int n = c < STAGE ? c : STAGE;
            int gp = atomicAdd(&gcur[b], n);
            int* rg = recs + (size_t)b * BUCKCAP + gp;
            for (int k = 0; k < n; ++k) rg[k] = stage[b][k];
        }
    }
}

// ---- pass B: one block per bucket; build ELL slice (L2-resident) + cnt -----
__global__ __launch_bounds__(256) void k_build(const int* __restrict__ recs,
                                               const int* __restrict__ gcur,
                                               int* __restrict__ ell,
                                               int* __restrict__ cnt, int N) {
    __shared__ int lcnt[256];
    int b = blockIdx.x;
    int t = threadIdx.x;
    lcnt[t] = 0;
    __syncthreads();
    int n = gcur[b]; if (n > BUCKCAP) n = BUCKCAP;
    const int* rp = recs + (size_t)b * BUCKCAP;
    int base = b << 8;
    for (int i = t; i < n; i += 256) {
        int rec = rp[i];
        int dl = rec & 255;
        int s = rec >> 8;
        int r = atomicAdd(&lcnt[dl], 1);
        if (r < MAXDEG) ell[(size_t)(base + dl) * MAXDEG + r] = s;
    }
    __syncthreads();
    int node = base + t;
    if (node < N) cnt[node] = lcnt[t];
}

// ---- prep: dinv + convert x -> s0 = 16*dinv*x (fp8 [N][32] uints) ----------
__global__ __launch_bounds__(256) void k_prep(const float4* __restrict__ x,
                                              const int* __restrict__ cnt,
                                              float* __restrict__ dinv,
                                              unsigned* __restrict__ g0, int N) {
    int t = threadIdx.x;
    int slot = t >> 5, lane = t & 31;
    int node = blockIdx.x * 8 + slot;
    if (node >= N) return;
    float sc = rsqrtf((float)cnt[node] + 1.0f);
    if (lane == 0) dinv[node] = sc;
    float m = sc * FP8_S;
    float4 v = x[(size_t)node * 32 + lane];     // features lane*4..+3
    g0[(size_t)node * 32 + lane] = fp8x4_pack(v.x * m, v.y * m, v.z * m, v.w * m);
}

// ---- aggregate: half-wave per node, 4B(fp8x4)/lane, 8 rows in flight -------
__global__ __launch_bounds__(256) void k_agg(const unsigned* __restrict__ gin,
                                             const int* __restrict__ ell,
                                             const int* __restrict__ cnt,
                                             float2* __restrict__ gout, int N) {
    int t = threadIdx.x;
    int slot = t >> 5;        // 0..7
    int lane = t & 31;
    int node = blockIdx.x * 8 + slot;
    if (node >= N) return;

    float2 a0 = make_float2(0.f, 0.f), a1 = make_float2(0.f, 0.f);
    fp8x4_acc(gin[(size_t)node * 32 + lane], a0, a1);   // self loop

    int deg = cnt[node]; if (deg > MAXDEG) deg = MAXDEG;
    const int* rowp = ell + (size_t)node * MAXDEG;
    int j = 0;
    for (; j + 7 < deg; j += 8) {
        int4 sa = *(const int4*)(rowp + j);
        int4 sb = *(const int4*)(rowp + j + 4);
        unsigned v0 = gin[(size_t)sa.x * 32 + lane];
        unsigned v1 = gin[(size_t)sa.y * 32 + lane];
        unsigned v2 = gin[(size_t)sa.z * 32 + lane];
        unsigned v3 = gin[(size_t)sa.w * 32 + lane];
        unsigned v4 = gin[(size_t)sb.x * 32 + lane];
        unsigned v5 = gin[(size_t)sb.y * 32 + lane];
        unsigned v6 = gin[(size_t)sb.z * 32 + lane];
        unsigned v7 = gin[(size_t)sb.w * 32 + lane];
        fp8x4_acc(v0, a0, a1); fp8x4_acc(v1, a0, a1);
        fp8x4_acc(v2, a0, a1); fp8x4_acc(v3, a0, a1);
        fp8x4_acc(v4, a0, a1); fp8x4_acc(v5, a0, a1);
        fp8x4_acc(v6, a0, a1); fp8x4_acc(v7, a0, a1);
    }
    for (; j + 3 < deg; j += 4) {
        int4 s4 = *(const int4*)(rowp + j);
        unsigned v0 = gin[(size_t)s4.x * 32 + lane];
        unsigned v1 = gin[(size_t)s4.y * 32 + lane];
        unsigned v2 = gin[(size_t)s4.z * 32 + lane];
        unsigned v3 = gin[(size_t)s4.w * 32 + lane];
        fp8x4_acc(v0, a0, a1); fp8x4_acc(v1, a0, a1);
        fp8x4_acc(v2, a0, a1); fp8x4_acc(v3, a0, a1);
    }
    for (; j < deg; ++j) {
        fp8x4_acc(gin[(size_t)rowp[j] * 32 + lane], a0, a1);
    }
    float2 o;   // 4 halfs: features lane*4..+3 (scaled by 16, fp16 holds it)
    ((__half2*)&o)[0] = __float22half2_rn(a0);
    ((__half2*)&o)[1] = __float22half2_rn(a1);
    gout[(size_t)node * 32 + lane] = o;
}

// ---- MFMA dense (layers 1,2): bufZ fp16 in, fp8(16*dinv*h) out -------------
__global__ __launch_bounds__(256) void k_gemm_mfma(
    const __half* __restrict__ in,   // [N][128] fp16 (16*agg)
    const __half* __restrict__ Wt,   // [128 f][128 k] fp16 (= W^T), L1-hot
    const float* __restrict__ bias,
    const float* __restrict__ dinv,
    unsigned* __restrict__ outp,     // fp8 [N][32] uints
    int N)
{
    int t = threadIdx.x;
    int wave = t >> 6, lane = t & 63;
    int ln31 = lane & 31;
    int khalf = lane >> 5;                     // 0/1
    int node = blockIdx.x * 128 + wave * 32 + ln31;
    bool valid = node < N;
    size_t nrow = (size_t)(valid ? node : 0) * 128;

    f16x8 bfrag[8];
    const f16x8* inrow = (const f16x8*)(in + nrow);
#pragma unroll
    for (int kc = 0; kc < 8; ++kc) bfrag[kc] = inrow[kc * 2 + khalf];

    float scn = dinv[valid ? node : 0];
    float epi = scn * FP8_INVS;                // undo 16x storage scale
    float sto = scn * FP8_S;                   // re-apply for next layer
    const float4* Wg4 = (const float4*)Wt;

#pragma unroll
    for (int ft = 0; ft < 4; ++ft) {
        f32x16 acc = {0.f, 0.f, 0.f, 0.f, 0.f, 0.f, 0.f, 0.f,
                      0.f, 0.f, 0.f, 0.f, 0.f, 0.f, 0.f, 0.f};
#pragma unroll
        for (int kc = 0; kc < 8; ++kc) {
            int aidx = (ft * 32 + ln31) * 16 + kc * 2 + khalf;
            f16x8 afrag = *(const f16x8*)&Wg4[aidx];
            acc = __builtin_amdgcn_mfma_f32_32x32x16_f16(afrag, bfrag[kc], acc, 0, 0, 0);
        }
        if (valid) {
#pragma unroll
            for (int q = 0; q < 4; ++q) {
                int f = ft * 32 + q * 8 + khalf * 4;
                float4 bb = *(const float4*)&bias[f];
                float o0 = fmaxf(acc[q * 4 + 0] * epi + bb.x, 0.f);
                float o1 = fmaxf(acc[q * 4 + 1] * epi + bb.y, 0.f);
                float o2 = fmaxf(acc[q * 4 + 2] * epi + bb.z, 0.f);
                float o3 = fmaxf(acc[q * 4 + 3] * epi + bb.w, 0.f);
                outp[(size_t)node * 32 + (f >> 2)] =
                    fp8x4_pack(o0 * sto, o1 * sto, o2 * sto, o3 * sto);
            }
        }
    }
}

// ---- layer 3: MFMA + fused mean-pool (fp16 in, fp32 pool, no h write) ------
__global__ __launch_bounds__(256) void k_gemm_pool(
    const __half* __restrict__ in,   // [N][128] fp16 (16*agg)
    const __half* __restrict__ Wt,
    const float* __restrict__ bias,
    const float* __restrict__ dinv,
    const int* __restrict__ batch,   // sorted
    float* __restrict__ pooled,      // [128][128], pre-zeroed
    float* __restrict__ gcnt,        // [128], pre-zeroed
    int N)
{
    __shared__ float pp[8][128];
    __shared__ float pc[8];
    int t = threadIdx.x;
    int nb = blockIdx.x * 128;
    int lastn = nb + 127; if (lastn > N - 1) lastn = N - 1;
    int gs = batch[nb];
    int ge = batch[lastn];
    int ng = ge - gs + 1;

    for (int i = t; i < 8 * 128; i += 256) ((float*)pp)[i] = 0.f;
    if (t < 8) pc[t] = 0.f;
    __syncthreads();

    int wave = t >> 6, lane = t & 63;
    int ln31 = lane & 31;
    int khalf = lane >> 5;
    int node = nb + wave * 32 + ln31;
    bool valid = node < N;
    size_t nrow = (size_t)(valid ? node : 0) * 128;
    int g_lane = valid ? batch[node] : -1;

    f16x8 bfrag[8];
    const f16x8* inrow = (const f16x8*)(in + nrow);
#pragma unroll
    for (int kc = 0; kc < 8; ++kc) bfrag[kc] = inrow[kc * 2 + khalf];

    float scn = dinv[valid ? node : 0];
    float epi = scn * FP8_INVS;
    const float4* Wg4 = (const float4*)Wt;

    for (int gg = 0; gg < ng; ++gg) {
        float cv = (khalf == 0 && g_lane == gs + gg) ? 1.f : 0.f;
#pragma unroll
        for (int m = 1; m <= 16; m <<= 1) cv += __shfl_xor(cv, m);
        if (lane == 0 && cv != 0.f) {
            if (gg < 8) atomicAdd(&pc[gg], cv);
            else        atomicAdd(&gcnt[gs + gg], cv);
        }
    }

#pragma unroll
    for (int ft = 0; ft < 4; ++ft) {
        f32x16 acc = {0.f, 0.f, 0.f, 0.f, 0.f, 0.f, 0.f, 0.f,
                      0.f, 0.f, 0.f, 0.f, 0.f, 0.f, 0.f, 0.f};
#pragma unroll
        for (int kc = 0; kc < 8; ++kc) {
            int aidx = (ft * 32 + ln31) * 16 + kc * 2 + khalf;
            f16x8 afrag = *(const f16x8*)&Wg4[aidx];
            acc = __builtin_amdgcn_mfma_f32_32x32x16_f16(afrag, bfrag[kc], acc, 0, 0, 0);
        }
#pragma unroll
        for (int q = 0; q < 4; ++q) {
            int f = ft * 32 + q * 8 + khalf * 4;
            float4 bb = *(const float4*)&bias[f];
            float h0 = fmaxf(acc[q * 4 + 0] * epi + bb.x, 0.f);
            float h1 = fmaxf(acc[q * 4 + 1] * epi + bb.y, 0.f);
            float h2 = fmaxf(acc[q * 4 + 2] * epi + bb.z, 0.f);
            float h3 = fmaxf(acc[q * 4 + 3] * epi + bb.w, 0.f);
            for (int gg = 0; gg < ng; ++gg) {
                int g = gs + gg;
                bool m = (g_lane == g);
                float v0 = m ? h0 : 0.f, v1 = m ? h1 : 0.f;
                float v2 = m ? h2 : 0.f, v3 = m ? h3 : 0.f;
#pragma unroll
                for (int mm = 1; mm <= 16; mm <<= 1) {
                    v0 += __shfl_xor(v0, mm);
                    v1 += __shfl_xor(v1, mm);
                    v2 += __shfl_xor(v2, mm);
                    v3 += __shfl_xor(v3, mm);
                }
                if (ln31 == 0) {
                    if (gg < 8) {
                        if (v0 != 0.f) atomicAdd(&pp[gg][f + 0], v0);
                        if (v1 != 0.f) atomicAdd(&pp[gg][f + 1], v1);
                        if (v2 != 0.f) atomicAdd(&pp[gg][f + 2], v2);
                        if (v3 != 0.f) atomicAdd(&pp[gg][f + 3], v3);
                    } else {
                        if (v0 != 0.f) atomicAdd(&pooled[g * 128 + f + 0], v0);
                        if (v1 != 0.f) atomicAdd(&pooled[g * 128 + f + 1], v1);
                        if (v2 != 0.f) atomicAdd(&pooled[g * 128 + f + 2], v2);
                        if (v3 != 0.f) atomicAdd(&pooled[g * 128 + f + 3], v3);
                    }
                }
            }
        }
    }
    __syncthreads();
    int ngc = ng < 8 ? ng : 8;
    if (t < 128) {
        for (int gg = 0; gg < ngc; ++gg) {
            float v = pp[gg][t];
            if (v != 0.f) atomicAdd(&pooled[(gs + gg) * 128 + t], v);
        }
    }
    if (t == 0) {
        for (int gg = 0; gg < ngc; ++gg)
            if (pc[gg] != 0.f) atomicAdd(&gcnt[gs + gg], pc[gg]);
    }
}

// ---- FFN: out[g] = relu(pooled_mean @ Wf1 + bf1) @ Wf2 + bf2 ---------------
__global__ __launch_bounds__(128) void k_ffn(const float* __restrict__ pooled,
                                             const float* __restrict__ gcnt,
                                             const float* __restrict__ Wf1,
                                             const float* __restrict__ bf1,
                                             const float* __restrict__ Wf2,
                                             const float* __restrict__ bf2,
                                             float* __restrict__ out, int C) {
    __shared__ float pl[128];
    __shared__ float hid[128];
    int g = blockIdx.x;
    int t = threadIdx.x;
    float invc = 1.0f / fmaxf(gcnt[g], 1.0f);
    pl[t] = pooled[g * 128 + t] * invc;
    __syncthreads();
    float s = bf1[t];
    for (int k = 0; k < 128; ++k) s += pl[k] * Wf1[k * 128 + t];
    hid[t] = fmaxf(s, 0.f);
    __syncthreads();
    if (t < C) {
        float o = bf2[t];
        for (int f = 0; f < 128; ++f) o += hid[f] * Wf2[f * C + t];
        out[g * C + t] = o;
    }
}

extern "C" void kernel_launch(void* const* d_in, const int* in_sizes, int n_in,
                              void* d_out, int out_size, void* d_ws, size_t ws_size,
                              hipStream_t stream) {
    const float* x   = (const float*)d_in[0];
    const int*   ei  = (const int*)d_in[1];
    const int*   bat = (const int*)d_in[2];
    const float* W1  = (const float*)d_in[3];
    const float* b1  = (const float*)d_in[4];
    const float* W2  = (const float*)d_in[5];
    const float* b2  = (const float*)d_in[6];
    const float* W3  = (const float*)d_in[7];
    const float* b3  = (const float*)d_in[8];
    const float* Wf1 = (const float*)d_in[9];
    const float* bf1 = (const float*)d_in[10];
    const float* Wf2 = (const float*)d_in[11];
    const float* bf2 = (const float*)d_in[12];
    float* out = (float*)d_out;

    int N = in_sizes[2];
    int E = in_sizes[1] / 2;
    int C = in_sizes[12];
    const int* row  = ei;
    const int* colv = ei + E;

    int nbuck = (N + 255) / 256;
    int Npad  = nbuck * 256;

    auto align256 = [](char* p) {
        return (char*)(((uintptr_t)p + 255) & ~(uintptr_t)255);
    };
    char* w = (char*)d_ws;
    unsigned* bufX8 = (unsigned*)w; w += (size_t)N * 128;   w = align256(w);
    unsigned* bufY8 = (unsigned*)w; w += (size_t)N * 128;   w = align256(w);
    __half* bufZ = (__half*)w; w += (size_t)N * 128 * 2;    w = align256(w);
    int* ell     = (int*)w;   w += (size_t)Npad * MAXDEG * 4; w = align256(w);
    int* recs    = (int*)w;   w += (size_t)nbuck * BUCKCAP * 4; w = align256(w);
    int* cnt     = (int*)w;   w += (size_t)Npad * 4;    w = align256(w);
    float* dinv  = (float*)w; w += (size_t)N * 4;       w = align256(w);
    int* gcur    = (int*)w;   w += NBUCKMAX * 4;        w = align256(w);
    __half* Wt1  = (__half*)w; w += 128 * 128 * 2;      w = align256(w);
    __half* Wt2  = (__half*)w; w += 128 * 128 * 2;      w = align256(w);
    __half* Wt3  = (__half*)w; w += 128 * 128 * 2;      w = align256(w);
    float* pooled= (float*)w;  w += 128 * 128 * 4;      w = align256(w);
    float* gcnt  = (float*)w;  w += 128 * 4;

    int nnode8 = (N + 7) / 8;
    int ngemm  = (N + 127) / 128;

    k_cvtw  <<<64, 256, 0, stream>>>(W1, W2, W3, Wt1, Wt2, Wt3, pooled, gcnt, gcur);
    k_bucket<<<512, 256, 0, stream>>>(row, colv, E, nbuck, gcur, recs);
    k_build <<<nbuck, 256, 0, stream>>>(recs, gcur, ell, cnt, N);
    k_prep  <<<nnode8, 256, 0, stream>>>((const float4*)x, cnt, dinv, bufX8, N);

    // layer 1: bufX8 -> agg bufZ -> gemm bufY8 (fp8, 16*dinv*h)
    k_agg <<<nnode8, 256, 0, stream>>>(bufX8, ell, cnt, (float2*)bufZ, N);
    k_gemm_mfma<<<ngemm, 256, 0, stream>>>(bufZ, Wt1, b1, dinv, bufY8, N);
    // layer 2: bufY8 -> agg bufZ -> gemm bufX8
    k_agg <<<nnode8, 256, 0, stream>>>(bufY8, ell, cnt, (float2*)bufZ, N);
    k_gemm_mfma<<<ngemm, 256, 0, stream>>>(bufZ, Wt2, b2, dinv, bufX8, N);
    // layer 3: bufX8 -> agg bufZ -> gemm+pool (no h write)
    k_agg <<<nnode8, 256, 0, stream>>>(bufX8, ell, cnt, (float2*)bufZ, N);
    k_gemm_pool<<<ngemm, 256, 0, stream>>>(bufZ, Wt3, b3, dinv, bat,
                                           pooled, gcnt, N);

    k_ffn <<<128, 128, 0, stream>>>(pooled, gcnt, Wf1, bf1, Wf2, bf2, out, C);
}